// Round 1
// baseline (566.597 us; speedup 1.0000x reference)
//
#include <hip/hip_runtime.h>
#include <hip/hip_bf16.h>

// ---------- types ----------
typedef __attribute__((ext_vector_type(8))) short bfrag8;   // 8 bf16 (4 VGPRs), MFMA A/B frag
typedef __attribute__((ext_vector_type(4))) float f32x4;    // MFMA C/D frag

__device__ __forceinline__ unsigned short f2bf(float f) {
  unsigned int u = __float_as_uint(f);
  u += 0x7FFFu + ((u >> 16) & 1u);   // RNE
  return (unsigned short)(u >> 16);
}

// torchvision _interp_axis semantics (aligned=false)
__device__ __forceinline__ void interp1(float t, int size, int& lo, int& hi, float& frac, bool& valid) {
  valid = (t > -1.0f) && (t < (float)size);
  t = fmaxf(t, 0.0f);
  lo = (int)floorf(t);
  if (lo > size - 1) lo = size - 1;
  hi = lo + 1; if (hi > size - 1) hi = size - 1;
  if (lo >= size - 1) t = (float)lo;   // frac forced to 0 at right edge
  frac = t - (float)lo;
}

// ---------- K1: RoI align -> A[256][37632] bf16, k' = c*49 + (ph*7+pw) ----------
// grid (3, 256): blockIdx.x = channel chunk (256 ch), blockIdx.y = box n. 256 thr.
__global__ __launch_bounds__(256) void roi_kernel(const float* __restrict__ fmap,
                                                  const float* __restrict__ boxes,
                                                  unsigned short* __restrict__ A) {
  const int chunk = blockIdx.x;
  const int n = blockIdx.y;
  const int t = threadIdx.x;
  __shared__ float lds[256 * 49];

  const float* bx = boxes + n * 5;
  const int b = (int)bx[0];
  const float x1 = bx[1], y1 = bx[2], x2 = bx[3], y2 = bx[4];
  const float bw = fmaxf(x2 - x1, 1.0f) * (1.0f / 7.0f);
  const float bh = fmaxf(y2 - y1, 1.0f) * (1.0f / 7.0f);

  const int c = chunk * 256 + t;
  const float* fb = fmap + (size_t)b * 64 * 64 * 768 + c;

  for (int ph = 0; ph < 7; ph++) {
    // y samples shared across pw
    int yl[2], yh[2]; float ly[2], hy[2]; bool vy[2];
    #pragma unroll
    for (int sy = 0; sy < 2; sy++) {
      float y = y1 + (ph * 2 + sy + 0.5f) * 0.5f * bh;
      interp1(y, 64, yl[sy], yh[sy], ly[sy], vy[sy]);
      hy[sy] = 1.0f - ly[sy];
    }
    for (int pw = 0; pw < 7; pw++) {
      float sum = 0.0f;
      #pragma unroll
      for (int sx = 0; sx < 2; sx++) {
        float x = x1 + (pw * 2 + sx + 0.5f) * 0.5f * bw;
        int xl, xh; float lx; bool vx;
        interp1(x, 64, xl, xh, lx, vx);
        float hx = 1.0f - lx;
        #pragma unroll
        for (int sy = 0; sy < 2; sy++) {
          if (vx && vy[sy]) {
            const float* r0 = fb + yl[sy] * 64 * 768;
            const float* r1 = fb + yh[sy] * 64 * 768;
            float v00 = r0[xl * 768], v01 = r0[xh * 768];
            float v10 = r1[xl * 768], v11 = r1[xh * 768];
            sum += hy[sy] * (hx * v00 + lx * v01) + ly[sy] * (hx * v10 + lx * v11);
          }
        }
      }
      lds[t * 49 + ph * 7 + pw] = sum * 0.25f;
    }
  }
  __syncthreads();
  unsigned short* out = A + (size_t)n * 37632 + chunk * 12544;
  for (int i = t; i < 12544; i += 256) out[i] = f2bf(lds[i]);
}

// ---------- K2/K4: split-K bf16 MFMA GEMM ----------
// A [256][KT] bf16 row-major; B [KT][NT] fp32 row-major (converted to bf16 in staging).
// grid (KT/CHUNK, NT/64); 256 thr (4 waves, each owns 64 rows x 64 cols).
// part[ks][m][n] fp32.
template<int KT, int NT, int CHUNK>
__global__ __launch_bounds__(256, 2) void gemm_splitk(const unsigned short* __restrict__ A,
                                                      const float* __restrict__ B,
                                                      float* __restrict__ part) {
  constexpr int STEPS = CHUNK / 64;
  const int ks = blockIdx.x, nt = blockIdx.y;
  const int n0 = nt * 64;
  const int k0 = ks * CHUNK;
  const int t = (int)threadIdx.x;
  const int lane = t & 63, wid = t >> 6;

  __shared__ unsigned short Al[256 * 72];  // [m][k], rows padded to 72 bf16 (144 B)
  __shared__ unsigned short Bl[64 * 72];   // [n][k], rows padded to 72 bf16

  f32x4 acc[4][4] = {};

  // staging register sets (double set for 1-step prefetch)
  uint4 aR0[8], aR1[8];
  float4 bR0[4], bR1[4];

  const int am = t >> 3;          // A base row (0..31), +32*i
  const int ak = (t & 7) * 8;     // A k offset (8 bf16 = 16B)
  const int bn = 4 * (t & 15);    // B n base
  const int bk = 2 * (t >> 4);    // B k base (even)

  auto loadA = [&](uint4* r, int s) {
    const unsigned short* p = A + (size_t)(k0 + s * 64 + ak);
    #pragma unroll
    for (int i = 0; i < 8; i++)
      r[i] = *reinterpret_cast<const uint4*>(p + (size_t)(am + i * 32) * KT);
  };
  auto loadB = [&](float4* r, int s) {
    #pragma unroll
    for (int j = 0; j < 2; j++) {
      const float* p = B + (size_t)(k0 + s * 64 + bk + 32 * j) * NT + n0 + bn;
      r[2 * j]     = *reinterpret_cast<const float4*>(p);
      r[2 * j + 1] = *reinterpret_cast<const float4*>(p + NT);
    }
  };
  auto stage = [&](const uint4* ra, const float4* rb) {
    #pragma unroll
    for (int i = 0; i < 8; i++)
      *reinterpret_cast<uint4*>(&Al[(am + i * 32) * 72 + ak]) = ra[i];
    #pragma unroll
    for (int j = 0; j < 2; j++) {
      #pragma unroll
      for (int i = 0; i < 4; i++) {
        int ii = (i + (t >> 2)) & 3;  // rotate write order -> spread LDS banks
        unsigned int pk = (unsigned int)f2bf(rb[2 * j][ii]) |
                          ((unsigned int)f2bf(rb[2 * j + 1][ii]) << 16);
        *reinterpret_cast<unsigned int*>(&Bl[(bn + ii) * 72 + bk + 32 * j]) = pk;
      }
    }
  };
  auto domfma = [&]() {
    #pragma unroll
    for (int kk = 0; kk < 2; kk++) {
      const int ko = kk * 32 + (lane >> 4) * 8;
      bfrag8 af[4], bf[4];
      #pragma unroll
      for (int fm = 0; fm < 4; fm++)
        af[fm] = *reinterpret_cast<const bfrag8*>(&Al[(wid * 64 + fm * 16 + (lane & 15)) * 72 + ko]);
      #pragma unroll
      for (int fn = 0; fn < 4; fn++)
        bf[fn] = *reinterpret_cast<const bfrag8*>(&Bl[(fn * 16 + (lane & 15)) * 72 + ko]);
      #pragma unroll
      for (int fm = 0; fm < 4; fm++)
        #pragma unroll
        for (int fn = 0; fn < 4; fn++)
          acc[fm][fn] = __builtin_amdgcn_mfma_f32_16x16x32_bf16(af[fm], bf[fn], acc[fm][fn], 0, 0, 0);
    }
  };

  loadA(aR0, 0); loadB(bR0, 0);
  for (int s = 0; s < STEPS; s += 2) {
    __syncthreads();
    stage(aR0, bR0);
    if (s + 1 < STEPS) { loadA(aR1, s + 1); loadB(bR1, s + 1); }
    __syncthreads();
    domfma();
    if (s + 1 < STEPS) {
      __syncthreads();
      stage(aR1, bR1);
      if (s + 2 < STEPS) { loadA(aR0, s + 2); loadB(bR0, s + 2); }
      __syncthreads();
      domfma();
    }
  }

  // epilogue: write fp32 partials. C/D layout: col=lane&15, row=(lane>>4)*4+q
  const int r4 = (lane >> 4) * 4, cn = lane & 15;
  #pragma unroll
  for (int fm = 0; fm < 4; fm++)
    #pragma unroll
    for (int fn = 0; fn < 4; fn++)
      #pragma unroll
      for (int q = 0; q < 4; q++) {
        int m = wid * 64 + fm * 16 + r4 + q;
        int n = n0 + fn * 16 + cn;
        part[(size_t)(ks * 256 + m) * NT + n] = acc[fm][fn][q];
      }
}

// ---------- K3: reduce 28 partials + bias + relu -> h bf16 [256][1024] ----------
__global__ __launch_bounds__(256) void reduce_relu_28(const float* __restrict__ part,
                                                      const float* __restrict__ b1,
                                                      unsigned short* __restrict__ h) {
  const int idx = blockIdx.x * 256 + threadIdx.x;  // < 262144
  float s = 0.0f;
  #pragma unroll
  for (int p = 0; p < 28; p++) s += part[(size_t)p * 262144 + idx];
  s += b1[idx & 1023];
  s = fmaxf(s, 0.0f);
  h[idx] = f2bf(s);
}

// ---------- K5: reduce 8 partials + bias -> out fp32 [256][512] ----------
__global__ __launch_bounds__(256) void reduce_bias_8(const float* __restrict__ part,
                                                     const float* __restrict__ b2,
                                                     float* __restrict__ out) {
  const int idx = blockIdx.x * 256 + threadIdx.x;  // < 131072
  float s = 0.0f;
  #pragma unroll
  for (int p = 0; p < 8; p++) s += part[(size_t)p * 131072 + idx];
  out[idx] = s + b2[idx & 511];
}

// ---------- launch ----------
extern "C" void kernel_launch(void* const* d_in, const int* in_sizes, int n_in,
                              void* d_out, int out_size, void* d_ws, size_t ws_size,
                              hipStream_t stream) {
  const float* fmap  = (const float*)d_in[0];
  const float* boxes = (const float*)d_in[1];
  const float* W1    = (const float*)d_in[2];
  const float* b1    = (const float*)d_in[3];
  const float* W2    = (const float*)d_in[4];
  const float* b2    = (const float*)d_in[5];
  float* out = (float*)d_out;

  char* ws = (char*)d_ws;
  unsigned short* Aroi = (unsigned short*)ws;                       // 256*37632*2   = 19,267,584
  float* part1 = (float*)(ws + 19267584);                           // 28*262144*4   = 29,360,128
  unsigned short* h = (unsigned short*)(ws + 19267584 + 29360128);  // 256*1024*2    =    524,288
  float* part2 = (float*)(ws + 19267584 + 29360128 + 524288);       // 8*131072*4    =  4,194,304

  // K1: RoI align -> A bf16
  roi_kernel<<<dim3(3, 256), 256, 0, stream>>>(fmap, boxes, Aroi);
  // K2: GEMM1 split-K: [256 x 37632] @ [37632 x 1024], S=28 (chunk 1344 = 21*64)
  gemm_splitk<37632, 1024, 1344><<<dim3(28, 16), 256, 0, stream>>>(Aroi, W1, part1);
  // K3: reduce + b1 + relu -> h bf16
  reduce_relu_28<<<1024, 256, 0, stream>>>(part1, b1, h);
  // K4: GEMM2 split-K: [256 x 1024] @ [1024 x 512], S=8 (chunk 128 = 2*64)
  gemm_splitk<1024, 512, 128><<<dim3(8, 8), 256, 0, stream>>>(h, W2, part2);
  // K5: reduce + b2 -> out fp32
  reduce_bias_8<<<512, 256, 0, stream>>>(part2, b2, out);
}

// Round 2
// 350.030 us; speedup vs baseline: 1.6187x; 1.6187x over previous
//
#include <hip/hip_runtime.h>
#include <hip/hip_bf16.h>

typedef __attribute__((ext_vector_type(8))) short bfrag8;   // 8 bf16 (4 VGPRs)
typedef __attribute__((ext_vector_type(4))) float f32x4;    // MFMA C/D frag

__device__ __forceinline__ unsigned short f2bf(float f) {
  unsigned int u = __float_as_uint(f);
  u += 0x7FFFu + ((u >> 16) & 1u);   // RNE
  return (unsigned short)(u >> 16);
}

// torchvision _interp_axis semantics (aligned=false)
__device__ __forceinline__ void interp1(float t, int size, int& lo, int& hi, float& frac, bool& valid) {
  valid = (t > -1.0f) && (t < (float)size);
  t = fmaxf(t, 0.0f);
  lo = (int)t;                      // t>=0 so trunc == floor
  if (lo > size - 1) lo = size - 1;
  hi = lo + 1; if (hi > size - 1) hi = size - 1;
  if (lo >= size - 1) t = (float)lo;
  frac = t - (float)lo;
}

// ---------- K1: RoI align -> A[256][37632] bf16, k'' = (ph*7+pw)*768 + c ----------
// grid (7, 256): x = ph, y = box. 192 threads, each owns channels 4t..4t+3 (float4).
__global__ __launch_bounds__(192) void roi_kernel(const float* __restrict__ fmap,
                                                  const float* __restrict__ boxes,
                                                  unsigned short* __restrict__ A) {
  const int ph = blockIdx.x;
  const int n  = blockIdx.y;
  const int t  = threadIdx.x;

  const float* bx = boxes + n * 5;
  const int b = (int)bx[0];
  const float x1 = bx[1], y1 = bx[2], x2 = bx[3], y2 = bx[4];
  const float bw = fmaxf(x2 - x1, 1.0f) * (1.0f / 7.0f);
  const float bh = fmaxf(y2 - y1, 1.0f) * (1.0f / 7.0f);

  const float* fb = fmap + (size_t)b * 64 * 64 * 768 + t * 4;

  int yl[2], yh[2]; float ly[2], hy[2]; bool vy[2];
  #pragma unroll
  for (int sy = 0; sy < 2; sy++) {
    float y = y1 + (ph * 2 + sy + 0.5f) * 0.5f * bh;
    interp1(y, 64, yl[sy], yh[sy], ly[sy], vy[sy]);
    hy[sy] = 1.0f - ly[sy];
  }

  float4 acc[7];
  #pragma unroll
  for (int pw = 0; pw < 7; pw++) acc[pw] = make_float4(0.f, 0.f, 0.f, 0.f);

  #pragma unroll
  for (int pw = 0; pw < 7; pw++) {
    #pragma unroll
    for (int sx = 0; sx < 2; sx++) {
      float x = x1 + (pw * 2 + sx + 0.5f) * 0.5f * bw;
      int xl, xh; float lx; bool vx;
      interp1(x, 64, xl, xh, lx, vx);
      float hx = 1.0f - lx;
      if (vx) {
        #pragma unroll
        for (int sy = 0; sy < 2; sy++) {
          if (vy[sy]) {   // box-uniform branch: wave-coherent
            float4 v00 = *(const float4*)(fb + (yl[sy] * 64 + xl) * 768);
            float4 v01 = *(const float4*)(fb + (yl[sy] * 64 + xh) * 768);
            float4 v10 = *(const float4*)(fb + (yh[sy] * 64 + xl) * 768);
            float4 v11 = *(const float4*)(fb + (yh[sy] * 64 + xh) * 768);
            float w00 = hy[sy] * hx, w01 = hy[sy] * lx, w10 = ly[sy] * hx, w11 = ly[sy] * lx;
            acc[pw].x += w00 * v00.x + w01 * v01.x + w10 * v10.x + w11 * v11.x;
            acc[pw].y += w00 * v00.y + w01 * v01.y + w10 * v10.y + w11 * v11.y;
            acc[pw].z += w00 * v00.z + w01 * v01.z + w10 * v10.z + w11 * v11.z;
            acc[pw].w += w00 * v00.w + w01 * v01.w + w10 * v10.w + w11 * v11.w;
          }
        }
      }
    }
  }

  unsigned short* arow = A + (size_t)n * 37632 + (size_t)(ph * 7) * 768 + t * 4;
  #pragma unroll
  for (int pw = 0; pw < 7; pw++) {
    float sx0 = acc[pw].x * 0.25f, sy0 = acc[pw].y * 0.25f;
    float sz0 = acc[pw].z * 0.25f, sw0 = acc[pw].w * 0.25f;
    uint2 pk;
    pk.x = (unsigned)f2bf(sx0) | ((unsigned)f2bf(sy0) << 16);
    pk.y = (unsigned)f2bf(sz0) | ((unsigned)f2bf(sw0) << 16);
    *(uint2*)(arow + (size_t)pw * 768) = pk;
  }
}

// ---------- K2/K4: split-K bf16 MFMA GEMM, BM=256 BN=64 BK=64 ----------
// A [256][KT] bf16 row-major (read via global_load_lds, source-swizzled).
// B [KT][NT] fp32; row index optionally permuted (PERM: k=bin*768+c -> W1 row c*49+bin).
// grid 1D = NKS*NNT, XCD-swizzled so all NNT n-tiles of a ks-chunk share an XCD.
template<int KT, int NT, int STEPS, int NNT, bool PERM>
__global__ __launch_bounds__(256, 2) void gemm_splitk(const unsigned short* __restrict__ A,
                                                      const float* __restrict__ B,
                                                      float* __restrict__ part) {
  __shared__ unsigned short Al[2][256 * 64];   // 64 KB, rows 128 B, XOR-swizzled content
  __shared__ unsigned short Bl[2][64 * 64];    // 16 KB, [n][k] rows 128 B, XOR-swizzled

  const int nwg = gridDim.x;
  const int bid = blockIdx.x;
  const int work = (bid & 7) * (nwg >> 3) + (bid >> 3);   // group ks-chunks per XCD
  const int ks = work / NNT;
  const int nt = work - ks * NNT;
  const int n0 = nt * 64;
  const int k0 = ks * (STEPS * 64);

  const int t = (int)threadIdx.x;
  const int lane = t & 63, wid = t >> 6;
  const int kp = t & 31;     // B staging: k-row pair (2kp, 2kp+1)
  const int nq = t >> 5;     // B staging: n-col group of 8

  f32x4 acc[4][4];
  #pragma unroll
  for (int i = 0; i < 4; i++)
    #pragma unroll
    for (int j = 0; j < 4; j++) acc[i][j] = (f32x4){0.f, 0.f, 0.f, 0.f};

  // B staging registers — NAMED variables, never address-taken (rule #20)
  float4 b_a0, b_a1, b_c0, b_c1;

  auto issueA = [&](int buf, int s) {
    #pragma unroll
    for (int i = 0; i < 8; i++) {
      const int r0 = wid * 64 + i * 8;                // 8 rows per 1KB instr
      const int row = r0 + (lane >> 3);
      const int j = (lane & 7) ^ (row & 7);           // pre-swizzled global slot
      const unsigned short* g = A + (size_t)row * KT + (k0 + s * 64 + j * 8);
      __builtin_amdgcn_global_load_lds(
          (const __attribute__((address_space(1))) void*)g,
          (__attribute__((address_space(3))) void*)&Al[buf][r0 * 64],
          16, 0, 0);
    }
  };

  auto loadB = [&](int s) {
    int k = k0 + s * 64 + 2 * kp;
    int r0, dr;
    if (PERM) { int bin = k / 768; int c = k - bin * 768; r0 = c * 49 + bin; dr = 49; }
    else      { r0 = k; dr = 1; }
    const float* p0 = B + (size_t)r0 * NT + n0 + nq * 8;
    const float* p1 = p0 + (size_t)dr * NT;
    b_a0 = *(const float4*)(p0);
    b_a1 = *(const float4*)(p0 + 4);
    b_c0 = *(const float4*)(p1);
    b_c1 = *(const float4*)(p1 + 4);
  };

  auto writeB = [&](int buf) {
    char* base = (char*)&Bl[buf][0];
    const int klo = (kp & 3) * 4, kslot = kp >> 2;
    int nrow = nq * 8;
    #define WR_B(ii, fa, fc) { \
      int r = nrow + ii; \
      unsigned v = (unsigned)f2bf(fa) | ((unsigned)f2bf(fc) << 16); \
      *(unsigned*)(base + r * 128 + ((kslot ^ (r & 7)) << 4) + klo) = v; }
    WR_B(0, b_a0.x, b_c0.x) WR_B(1, b_a0.y, b_c0.y)
    WR_B(2, b_a0.z, b_c0.z) WR_B(3, b_a0.w, b_c0.w)
    WR_B(4, b_a1.x, b_c1.x) WR_B(5, b_a1.y, b_c1.y)
    WR_B(6, b_a1.z, b_c1.z) WR_B(7, b_a1.w, b_c1.w)
    #undef WR_B
  };

  auto compute = [&](int buf) {
    const char* abase = (const char*)&Al[buf][0];
    const char* bbase = (const char*)&Bl[buf][0];
    #pragma unroll
    for (int kk = 0; kk < 2; kk++) {
      const int slot = kk * 4 + (lane >> 4);
      bfrag8 af[4], bf[4];
      #pragma unroll
      for (int fm = 0; fm < 4; fm++) {
        const int r = wid * 64 + fm * 16 + (lane & 15);
        af[fm] = *(const bfrag8*)(abase + r * 128 + ((slot ^ (r & 7)) << 4));
      }
      #pragma unroll
      for (int fn = 0; fn < 4; fn++) {
        const int r = fn * 16 + (lane & 15);
        bf[fn] = *(const bfrag8*)(bbase + r * 128 + ((slot ^ (r & 7)) << 4));
      }
      #pragma unroll
      for (int fm = 0; fm < 4; fm++)
        #pragma unroll
        for (int fn = 0; fn < 4; fn++)
          acc[fm][fn] = __builtin_amdgcn_mfma_f32_16x16x32_bf16(af[fm], bf[fn], acc[fm][fn], 0, 0, 0);
    }
  };

  // prologue
  issueA(0, 0);
  loadB(0);
  writeB(0);
  __syncthreads();           // drains vmcnt(0): A-glds + B loads complete

  int buf = 0;
  for (int s = 0; s < STEPS; s++) {
    if (s + 1 < STEPS) {
      issueA(buf ^ 1, s + 1);   // async into other half
      loadB(s + 1);             // HBM latency hides under compute
    }
    compute(buf);
    if (s + 1 < STEPS) writeB(buf ^ 1);
    __syncthreads();
    buf ^= 1;
  }

  // epilogue: C/D layout col=lane&15, row=(lane>>4)*4+q
  const int r4 = (lane >> 4) * 4, cn = lane & 15;
  #pragma unroll
  for (int fm = 0; fm < 4; fm++)
    #pragma unroll
    for (int fn = 0; fn < 4; fn++)
      #pragma unroll
      for (int q = 0; q < 4; q++) {
        int m = wid * 64 + fm * 16 + r4 + q;
        part[((size_t)ks * 256 + m) * NT + n0 + fn * 16 + cn] = acc[fm][fn][q];
      }
}

// ---------- K3: reduce 28 partials + bias + relu -> h bf16 [256][1024] ----------
__global__ __launch_bounds__(256) void reduce_relu_28(const float* __restrict__ part,
                                                      const float* __restrict__ b1,
                                                      unsigned short* __restrict__ h) {
  const int i4 = blockIdx.x * 256 + threadIdx.x;   // over 65536 float4
  const float4* p4 = (const float4*)part;
  float4 s = p4[i4];
  #pragma unroll
  for (int p = 1; p < 28; p++) {
    float4 v = p4[(size_t)p * 65536 + i4];
    s.x += v.x; s.y += v.y; s.z += v.z; s.w += v.w;
  }
  float4 bb = ((const float4*)b1)[i4 & 255];
  s.x = fmaxf(s.x + bb.x, 0.f); s.y = fmaxf(s.y + bb.y, 0.f);
  s.z = fmaxf(s.z + bb.z, 0.f); s.w = fmaxf(s.w + bb.w, 0.f);
  uint2 pk;
  pk.x = (unsigned)f2bf(s.x) | ((unsigned)f2bf(s.y) << 16);
  pk.y = (unsigned)f2bf(s.z) | ((unsigned)f2bf(s.w) << 16);
  ((uint2*)h)[i4] = pk;
}

// ---------- K5: reduce 8 partials + bias -> out fp32 [256][512] ----------
__global__ __launch_bounds__(256) void reduce_bias_8(const float* __restrict__ part,
                                                     const float* __restrict__ b2,
                                                     float* __restrict__ out) {
  const int i4 = blockIdx.x * 256 + threadIdx.x;   // over 32768 float4
  const float4* p4 = (const float4*)part;
  float4 s = p4[i4];
  #pragma unroll
  for (int p = 1; p < 8; p++) {
    float4 v = p4[(size_t)p * 32768 + i4];
    s.x += v.x; s.y += v.y; s.z += v.z; s.w += v.w;
  }
  float4 bb = ((const float4*)b2)[i4 & 127];
  s.x += bb.x; s.y += bb.y; s.z += bb.z; s.w += bb.w;
  ((float4*)out)[i4] = s;
}

// ---------- launch ----------
extern "C" void kernel_launch(void* const* d_in, const int* in_sizes, int n_in,
                              void* d_out, int out_size, void* d_ws, size_t ws_size,
                              hipStream_t stream) {
  const float* fmap  = (const float*)d_in[0];
  const float* boxes = (const float*)d_in[1];
  const float* W1    = (const float*)d_in[2];
  const float* b1    = (const float*)d_in[3];
  const float* W2    = (const float*)d_in[4];
  const float* b2    = (const float*)d_in[5];
  float* out = (float*)d_out;

  char* ws = (char*)d_ws;
  unsigned short* Aroi = (unsigned short*)ws;                       // 19,267,584 B
  float* part1 = (float*)(ws + 19267584);                           // 28*1MB = 29,360,128 B
  unsigned short* h = (unsigned short*)(ws + 19267584 + 29360128);  // 524,288 B
  float* part2 = (float*)(ws + 19267584 + 29360128 + 524288);       // 4,194,304 B

  // K1: RoI align -> A bf16 (k-order: bin-major)
  roi_kernel<<<dim3(7, 256), 192, 0, stream>>>(fmap, boxes, Aroi);
  // K2: GEMM1 [256 x 37632] @ perm(W1) [37632 x 1024], 28 ks x 16 nt
  gemm_splitk<37632, 1024, 21, 16, true><<<448, 256, 0, stream>>>(Aroi, W1, part1);
  // K3: reduce + b1 + relu -> h bf16
  reduce_relu_28<<<256, 256, 0, stream>>>(part1, b1, h);
  // K4: GEMM2 [256 x 1024] @ W2 [1024 x 512], 8 ks x 8 nt
  gemm_splitk<1024, 512, 2, 8, false><<<64, 256, 0, stream>>>(h, W2, part2);
  // K5: reduce + b2 -> out
  reduce_bias_8<<<128, 256, 0, stream>>>(part2, b2, out);
}